// Round 1
// baseline (7679.920 us; speedup 1.0000x reference)
//
#include <hip/hip_runtime.h>
#include <hip/hip_bf16.h>
#include <math.h>

// Problem constants
// B=16384, NB=8, NA=16, D=128, IN_DIM=2304, QK_DIM=384, V_DIM=128
static constexpr size_t OFF_ATT = 262144;      // attended_sf
static constexpr size_t OFF_LOG = 33816576;    // attn_logits
static constexpr size_t OFF_W   = 33947648;    // attention_weights
static constexpr size_t OFF_KM  = 34078720;    // keys_masked
static constexpr size_t OFF_VM  = 84410368;    // values_masked
static constexpr size_t OFF_SIM = 352845824;   // sim (7)

__device__ inline float wave_sum(float v) {
#pragma unroll
  for (int o = 32; o > 0; o >>= 1) v += __shfl_xor(v, o, 64);
  return v;
}

// One wave per (b,n) row: inverse L2 norm of task rows. Also zero sim slots.
__global__ void norm_kernel(const float* __restrict__ task, float* __restrict__ invn,
                            float* __restrict__ simo) {
  int idx = blockIdx.x * 4 + (threadIdx.x >> 6);
  int lane = threadIdx.x & 63;
  float t0 = task[(size_t)idx * 128 + lane];
  float t1 = task[(size_t)idx * 128 + 64 + lane];
  float s = wave_sum(t0 * t0 + t1 * t1);
  if (lane == 0) invn[idx] = rsqrtf(s);
  if (blockIdx.x == 0 && threadIdx.x < 7) simo[threadIdx.x] = 0.0f;
}

// One block per b: RBF similarity of consecutive bst rows (double-buffered in LDS).
__global__ void sim_kernel(const float* __restrict__ basis, const float* __restrict__ sf,
                           const float* __restrict__ task, const float* __restrict__ invn,
                           float* __restrict__ simo) {
  int b = blockIdx.x;
  int tid = threadIdx.x;
  __shared__ float buf[2][2304];
  __shared__ float wred[4];
  {
    float iv = invn[(size_t)b * 8 + 0];
    for (int k = tid; k < 2304; k += 256) {
      float v;
      if (k < 128)       v = basis[(size_t)(b * 8 + 0) * 128 + k];
      else if (k < 2176) v = sf[(size_t)(b * 8 + 0) * 2048 + (k - 128)];
      else               v = task[(size_t)(b * 8 + 0) * 128 + (k - 2176)] * iv;
      buf[0][k] = v;
    }
  }
  __syncthreads();
  for (int n = 1; n < 8; ++n) {
    float iv = invn[(size_t)b * 8 + n];
    int cur = n & 1;
    for (int k = tid; k < 2304; k += 256) {
      float v;
      if (k < 128)       v = basis[(size_t)(b * 8 + n) * 128 + k];
      else if (k < 2176) v = sf[(size_t)(b * 8 + n) * 2048 + (k - 128)];
      else               v = task[(size_t)(b * 8 + n) * 128 + (k - 2176)] * iv;
      buf[cur][k] = v;
    }
    __syncthreads();
    float p = 0.f;
    for (int k = tid; k < 2304; k += 256) {
      float d = buf[cur][k] - buf[cur ^ 1][k];
      p += d * d;
    }
    p = wave_sum(p);
    if ((tid & 63) == 0) wred[tid >> 6] = p;
    __syncthreads();
    if (tid == 0) {
      float s = wred[0] + wred[1] + wred[2] + wred[3];
      atomicAdd(&simo[n - 1], expf(-0.5f * s) * (1.0f / 16384.0f));
    }
    __syncthreads();
  }
}

// Generic f32 GEMM: out[M x Nout] = A[M x K] @ W[K x Nout] (+bias)(*mask)
// MODE 0: keys   A row m=(b*8+n): [basis | sf | task*invn], K=2304, +bk, *mask_rep
// MODE 1: query  A row m=b (n=0 slices), K=2304
// MODE 2: values A row m = sf row, K=128, +bv
// Tile 128x128, BK=32, 256 threads, 8x8 per thread. A stored K-major in LDS (pitch 132).
template <int MODE>
__global__ void gemm_kernel(const float* __restrict__ basis, const float* __restrict__ sf,
                            const float* __restrict__ task, const float* __restrict__ invn,
                            const float* __restrict__ W, const float* __restrict__ bias,
                            const float* __restrict__ mask, float* __restrict__ out,
                            int Ntiles, int Ksteps, int ldw, int ldout) {
  __shared__ float As[32 * 132];
  __shared__ float Bs[32 * 132];
  int bx = blockIdx.x;
  int nt = bx % Ntiles;
  int mt = bx / Ntiles;
  int tid = threadIdx.x;
  int tx = tid & 15, ty = tid >> 4;
  int n0 = nt * 128;
  int m0 = mt * 128;
  float acc[8][8];
#pragma unroll
  for (int i = 0; i < 8; ++i)
#pragma unroll
    for (int j = 0; j < 8; ++j) acc[i][j] = 0.f;

  for (int ks = 0; ks < Ksteps; ++ks) {
    int k0 = ks * 32;
#pragma unroll
    for (int i = 0; i < 4; ++i) {
      int fi = tid + i * 256;
      int ml = fi >> 3;
      int kl = (fi & 7) * 4;
      int m = m0 + ml;
      int k = k0 + kl;
      float4 v;
      if (MODE == 2) {
        v = *(const float4*)(sf + (size_t)m * 128 + k);
      } else if (MODE == 0) {
        if (k0 < 128)       v = *(const float4*)(basis + (size_t)m * 128 + k);
        else if (k0 < 2176) v = *(const float4*)(sf + (size_t)m * 2048 + (k - 128));
        else {
          v = *(const float4*)(task + (size_t)m * 128 + (k - 2176));
          float s = invn[m];
          v.x *= s; v.y *= s; v.z *= s; v.w *= s;
        }
      } else {
        if (k0 < 128)       v = *(const float4*)(basis + (size_t)m * 1024 + k);
        else if (k0 < 2176) v = *(const float4*)(sf + (size_t)m * 16384 + (k - 128));
        else {
          v = *(const float4*)(task + (size_t)m * 1024 + (k - 2176));
          float s = invn[(size_t)m * 8];
          v.x *= s; v.y *= s; v.z *= s; v.w *= s;
        }
      }
      As[(kl + 0) * 132 + ml] = v.x;
      As[(kl + 1) * 132 + ml] = v.y;
      As[(kl + 2) * 132 + ml] = v.z;
      As[(kl + 3) * 132 + ml] = v.w;
    }
#pragma unroll
    for (int i = 0; i < 4; ++i) {
      int fi = tid + i * 256;
      int kk = fi >> 5;
      int cq = fi & 31;
      float4 v = *(const float4*)(W + (size_t)(k0 + kk) * ldw + n0 + cq * 4);
      *(float4*)(Bs + kk * 132 + cq * 4) = v;
    }
    __syncthreads();
#pragma unroll
    for (int kk = 0; kk < 32; ++kk) {
      float4 a0 = *(const float4*)(As + kk * 132 + ty * 8);
      float4 a1 = *(const float4*)(As + kk * 132 + ty * 8 + 4);
      float4 b0 = *(const float4*)(Bs + kk * 132 + tx * 8);
      float4 b1 = *(const float4*)(Bs + kk * 132 + tx * 8 + 4);
      float a[8]  = {a0.x, a0.y, a0.z, a0.w, a1.x, a1.y, a1.z, a1.w};
      float bb[8] = {b0.x, b0.y, b0.z, b0.w, b1.x, b1.y, b1.z, b1.w};
#pragma unroll
      for (int i = 0; i < 8; ++i)
#pragma unroll
        for (int j = 0; j < 8; ++j) acc[i][j] = fmaf(a[i], bb[j], acc[i][j]);
    }
    __syncthreads();
  }
#pragma unroll
  for (int i = 0; i < 8; ++i) {
    int row = m0 + ty * 8 + i;
    float vv[8];
#pragma unroll
    for (int j = 0; j < 8; ++j) {
      int c = n0 + tx * 8 + j;
      float v = acc[i][j];
      if (MODE == 0)      v = (v + bias[c]) * mask[(size_t)row * 128 + (unsigned)c / 3u];
      else if (MODE == 2) v = v + bias[c];
      vv[j] = v;
    }
    *(float4*)(out + (size_t)row * ldout + n0 + tx * 8)     = make_float4(vv[0], vv[1], vv[2], vv[3]);
    *(float4*)(out + (size_t)row * ldout + n0 + tx * 8 + 4) = make_float4(vv[4], vv[5], vv[6], vv[7]);
  }
}

// One block per b: logits (dot of query with 8 masked keys), where(==0), softmax.
__global__ void attn_kernel(const float* __restrict__ query, const float* __restrict__ km,
                            float* __restrict__ logits, float* __restrict__ wts) {
  int b = blockIdx.x;
  int tid = threadIdx.x;
  int w = tid >> 6, lane = tid & 63;
  __shared__ float lg[8];
  __shared__ float post[8];
  __shared__ float ex[8];
  for (int n = w; n < 8; n += 4) {
    float p = 0.f;
    for (int k = lane; k < 384; k += 64)
      p += query[(size_t)b * 384 + k] * km[((size_t)b * 8 + n) * 384 + k];
    p = wave_sum(p);
    if (lane == 0) lg[n] = p * 0.08838834764831845f;  // 1/sqrt(128)
  }
  __syncthreads();
  if (tid < 8) {
    float l = lg[tid];
    l = (l == 0.0f) ? -1e9f : l;
    post[tid] = l;
    logits[(size_t)b * 8 + tid] = l;
  }
  __syncthreads();
  if (tid < 8) {
    float m = post[0];
#pragma unroll
    for (int i = 1; i < 8; ++i) m = fmaxf(m, post[i]);
    ex[tid] = expf(post[tid] - m);
  }
  __syncthreads();
  if (tid < 8) {
    float s = 0.f;
#pragma unroll
    for (int i = 0; i < 8; ++i) s += ex[i];
    wts[(size_t)b * 8 + tid] = ex[tid] / s;
  }
}

// One block per b: attended_sf = sum_n w_n * values[b,n,:,:]; q_1 = task0 . attended rows.
__global__ void attend_kernel(const float* __restrict__ wts, const float* __restrict__ vm,
                              const float* __restrict__ task,
                              float* __restrict__ att, float* __restrict__ q1) {
  int b = blockIdx.x;
  int tid = threadIdx.x;
  __shared__ float attL[2048];
  float w[8];
#pragma unroll
  for (int n = 0; n < 8; ++n) w[n] = wts[(size_t)b * 8 + n];
#pragma unroll
  for (int i = 0; i < 8; ++i) {
    int idx = tid + i * 256;
    float a = 0.f;
#pragma unroll
    for (int n = 0; n < 8; ++n) a = fmaf(w[n], vm[((size_t)b * 8 + n) * 2048 + idx], a);
    att[(size_t)b * 2048 + idx] = a;
    attL[idx] = a;
  }
  __syncthreads();
  int wv = tid >> 6, lane = tid & 63;
  for (int j = wv; j < 16; j += 4) {
    float p = task[(size_t)b * 1024 + lane] * attL[j * 128 + lane]
            + task[(size_t)b * 1024 + 64 + lane] * attL[j * 128 + 64 + lane];
    p = wave_sum(p);
    if (lane == 0) q1[(size_t)b * 16 + j] = p;
  }
}

extern "C" void kernel_launch(void* const* d_in, const int* in_sizes, int n_in,
                              void* d_out, int out_size, void* d_ws, size_t ws_size,
                              hipStream_t stream) {
  const float* basis = (const float*)d_in[0];
  const float* sf    = (const float*)d_in[1];
  const float* task  = (const float*)d_in[2];
  const float* mask  = (const float*)d_in[3];
  const float* Wq    = (const float*)d_in[4];
  const float* Wk    = (const float*)d_in[5];
  const float* bk    = (const float*)d_in[6];
  const float* Wv    = (const float*)d_in[7];
  const float* bv    = (const float*)d_in[8];

  float* out  = (float*)d_out;
  float* q1   = out;
  float* att  = out + OFF_ATT;
  float* logi = out + OFF_LOG;
  float* wts  = out + OFF_W;
  float* km   = out + OFF_KM;
  float* vm   = out + OFF_VM;
  float* simo = out + OFF_SIM;

  // scratch: invn (B*8 f32) + query (B*384 f32). Fall back to stashing in the
  // attended_sf output region (only overwritten by the final kernel) if ws is small.
  float* invn;
  float* query;
  size_t need = (size_t)(131072 + 6291456) * sizeof(float);
  if (ws_size >= need) {
    invn = (float*)d_ws;
    query = invn + 131072;
  } else {
    query = att;
    invn = att + 6291456;
  }

  norm_kernel<<<32768, 256, 0, stream>>>(task, invn, simo);
  sim_kernel<<<16384, 256, 0, stream>>>(basis, sf, task, invn, simo);
  // values: M = 2,097,152 rows of sf, K=128, N=128
  gemm_kernel<2><<<16384, 256, 0, stream>>>(basis, sf, task, invn, Wv, bv, nullptr, vm,
                                            1, 4, 128, 128);
  // keys: M = 131072, K=2304, N=384 (+bk, *mask_rep)
  gemm_kernel<0><<<3072, 256, 0, stream>>>(basis, sf, task, invn, Wk, bk, mask, km,
                                           3, 72, 384, 384);
  // query: M = 16384, K=2304, N=384
  gemm_kernel<1><<<384, 256, 0, stream>>>(basis, sf, task, invn, Wq, nullptr, nullptr, query,
                                          3, 72, 384, 384);
  attn_kernel<<<16384, 256, 0, stream>>>(query, km, logi, wts);
  attend_kernel<<<16384, 256, 0, stream>>>(wts, vm, task, att, q1);
}

// Round 2
// 2811.111 us; speedup vs baseline: 2.7320x; 2.7320x over previous
//
#include <hip/hip_runtime.h>
#include <hip/hip_bf16.h>
#include <math.h>

// B=16384, NB=8, NA=16, D=128, IN_DIM=2304, QK_DIM=384, V_DIM=128
static constexpr size_t OFF_ATT = 262144;      // attended_sf (33,554,432 f32)
static constexpr size_t OFF_LOG = 33816576;    // attn_logits
static constexpr size_t OFF_W   = 33947648;    // attention_weights
static constexpr size_t OFF_KM  = 34078720;    // keys_masked
static constexpr size_t OFF_VM  = 84410368;    // values_masked (268,435,456 f32)
static constexpr size_t OFF_SIM = 352845824;   // sim (7)

typedef short bf16x8 __attribute__((ext_vector_type(8)));
typedef float f32x4 __attribute__((ext_vector_type(4)));

__device__ inline unsigned short f2bf(float f) {
  union { float f; unsigned u; } x; x.f = f;
  unsigned r = x.u + 0x7FFFu + ((x.u >> 16) & 1u);  // RNE
  return (unsigned short)(r >> 16);
}

__device__ inline float wave_sum(float v) {
#pragma unroll
  for (int o = 32; o > 0; o >>= 1) v += __shfl_xor(v, o, 64);
  return v;
}

// One wave per (b,n) row: inverse L2 norm of task rows. Also zero sim slots.
__global__ void norm_kernel(const float* __restrict__ task, float* __restrict__ invn,
                            float* __restrict__ simo) {
  int idx = blockIdx.x * 4 + (threadIdx.x >> 6);
  int lane = threadIdx.x & 63;
  float t0 = task[(size_t)idx * 128 + lane];
  float t1 = task[(size_t)idx * 128 + 64 + lane];
  float s = wave_sum(t0 * t0 + t1 * t1);
  if (lane == 0) invn[idx] = rsqrtf(s);
  if (blockIdx.x == 0 && threadIdx.x < 7) simo[threadIdx.x] = 0.0f;
}

// Transpose + cvt weights: WkT/WqT [384][2304] bf16, WvT [128][128] bf16.
__global__ void wprep_kernel(const float* __restrict__ Wk, const float* __restrict__ Wq,
                             const float* __restrict__ Wv,
                             unsigned short* __restrict__ WkT, unsigned short* __restrict__ WqT,
                             unsigned short* __restrict__ WvT) {
  int b = blockIdx.x, tid = threadIdx.x;
  if (b < 384) {
    for (int k = tid; k < 2304; k += 256) WkT[(size_t)b * 2304 + k] = f2bf(Wk[(size_t)k * 384 + b]);
  } else if (b < 768) {
    int n = b - 384;
    for (int k = tid; k < 2304; k += 256) WqT[(size_t)n * 2304 + k] = f2bf(Wq[(size_t)k * 384 + n]);
  } else {
    int base = (b - 768) * 16;
    for (int i = tid; i < 16 * 128; i += 256) {
      int n = base + (i >> 7), k = i & 127;
      WvT[(size_t)n * 128 + k] = f2bf(Wv[(size_t)k * 128 + n]);
    }
  }
}

// One block per b: build Abf rows (bf16 [131072][2304]) and fused sim reduction.
__global__ void abuild_sim_kernel(const float* __restrict__ basis, const float* __restrict__ sf,
                                  const float* __restrict__ task, const float* __restrict__ invn,
                                  unsigned short* __restrict__ Abf, float* __restrict__ simo) {
  int b = blockIdx.x, tid = threadIdx.x;
  __shared__ float buf[2][2304];
  __shared__ float wred[4];
  for (int n = 0; n < 8; ++n) {
    int cur = n & 1;
    size_t row = (size_t)b * 8 + n;
    float iv = invn[row];
    for (int idx = tid; idx < 576; idx += 256) {
      float4 v;
      if (idx < 32)       v = *(const float4*)(basis + row * 128 + idx * 4);
      else if (idx < 544) v = *(const float4*)(sf + row * 2048 + (idx - 32) * 4);
      else {
        v = *(const float4*)(task + row * 128 + (idx - 544) * 4);
        v.x *= iv; v.y *= iv; v.z *= iv; v.w *= iv;
      }
      buf[cur][idx * 4 + 0] = v.x; buf[cur][idx * 4 + 1] = v.y;
      buf[cur][idx * 4 + 2] = v.z; buf[cur][idx * 4 + 3] = v.w;
      ushort4 o = make_ushort4(f2bf(v.x), f2bf(v.y), f2bf(v.z), f2bf(v.w));
      *(ushort4*)(Abf + row * 2304 + idx * 4) = o;
    }
    __syncthreads();
    if (n > 0) {
      float p = 0.f;
      for (int k = tid; k < 2304; k += 256) {
        float d = buf[cur][k] - buf[cur ^ 1][k];
        p += d * d;
      }
      p = wave_sum(p);
      if ((tid & 63) == 0) wred[tid >> 6] = p;
      __syncthreads();
      if (tid == 0) {
        float s = wred[0] + wred[1] + wred[2] + wred[3];
        atomicAdd(&simo[n - 1], expf(-0.5f * s) * (1.0f / 16384.0f));
      }
    }
    __syncthreads();
  }
}

// MFMA GEMM for keys (MODE 0) / query (MODE 1): out[M x 384] = Abf rows @ WT^T.
// 128x128 tile, BK=32, 4 waves (2x2 of 64x64), acc 4x4 fragments per wave.
template <int MODE>
__global__ __launch_bounds__(256) void qk_gemm(const unsigned short* __restrict__ Abf,
                                               const unsigned short* __restrict__ WT,
                                               const float* __restrict__ bias,
                                               const float* __restrict__ mask,
                                               float* __restrict__ outp) {
  __shared__ unsigned short As[128 * 40];
  __shared__ unsigned short Bs[128 * 40];
  int nwg = gridDim.x, per = nwg >> 3;
  int bid = blockIdx.x;
  int swz = (bid & 7) * per + (bid >> 3);
  int mt = swz / 3, nt = swz - mt * 3;
  int tid = threadIdx.x;
  int wave = tid >> 6, lane = tid & 63;
  int wr = wave >> 1, wc = wave & 1;
  int r = tid >> 1, h = tid & 1;

  f32x4 acc[4][4];
#pragma unroll
  for (int i = 0; i < 4; ++i)
#pragma unroll
    for (int j = 0; j < 4; ++j) acc[i][j] = (f32x4)(0.f);

  size_t arow = (MODE == 1) ? (size_t)(mt * 128 + r) * 8 : (size_t)(mt * 128 + r);
  const unsigned short* aptr = Abf + arow * 2304 + h * 16;
  const unsigned short* bptr = WT + (size_t)(nt * 128 + r) * 2304 + h * 16;
  int la = lane & 15, lk = (lane >> 4) * 8;

  for (int ks = 0; ks < 72; ++ks) {
    int k0 = ks * 32;
    bf16x8 a0 = *(const bf16x8*)(aptr + k0);
    bf16x8 a1 = *(const bf16x8*)(aptr + k0 + 8);
    bf16x8 b0 = *(const bf16x8*)(bptr + k0);
    bf16x8 b1 = *(const bf16x8*)(bptr + k0 + 8);
    *(bf16x8*)(As + r * 40 + h * 16)     = a0;
    *(bf16x8*)(As + r * 40 + h * 16 + 8) = a1;
    *(bf16x8*)(Bs + r * 40 + h * 16)     = b0;
    *(bf16x8*)(Bs + r * 40 + h * 16 + 8) = b1;
    __syncthreads();
    bf16x8 af[4], bf[4];
#pragma unroll
    for (int mi = 0; mi < 4; ++mi)
      af[mi] = *(const bf16x8*)(As + (wr * 64 + mi * 16 + la) * 40 + lk);
#pragma unroll
    for (int ni = 0; ni < 4; ++ni)
      bf[ni] = *(const bf16x8*)(Bs + (wc * 64 + ni * 16 + la) * 40 + lk);
#pragma unroll
    for (int mi = 0; mi < 4; ++mi)
#pragma unroll
      for (int ni = 0; ni < 4; ++ni)
        acc[mi][ni] = __builtin_amdgcn_mfma_f32_16x16x32_bf16(af[mi], bf[ni], acc[mi][ni], 0, 0, 0);
    __syncthreads();
  }

  int rq = lane >> 4;
#pragma unroll
  for (int mi = 0; mi < 4; ++mi) {
#pragma unroll
    for (int ni = 0; ni < 4; ++ni) {
      int colg = nt * 128 + wc * 64 + ni * 16 + la;
#pragma unroll
      for (int j = 0; j < 4; ++j) {
        int rowg = mt * 128 + wr * 64 + mi * 16 + rq * 4 + j;
        float v = acc[mi][ni][j];
        if (MODE == 0)
          v = (v + bias[colg]) * mask[(size_t)rowg * 128 + (unsigned)colg / 3u];
        outp[(size_t)rowg * 384 + colg] = v;
      }
    }
  }
}

// MFMA values GEMM: vm[2M x 128] = sf[2M x 128] @ Wv + bv. B staged once.
__global__ __launch_bounds__(256) void v_gemm(const float* __restrict__ sf,
                                              const unsigned short* __restrict__ WvT,
                                              const float* __restrict__ bv,
                                              float* __restrict__ vm) {
  __shared__ unsigned short As[128 * 40];
  __shared__ unsigned short Bs[128 * 136];
  int bid = blockIdx.x;
  int swz = (bid & 7) * 2048 + (bid >> 3);
  size_t m0 = (size_t)swz * 128;
  int tid = threadIdx.x;
  int wave = tid >> 6, lane = tid & 63;
  int wr = wave >> 1, wc = wave & 1;
  int r = tid >> 1, h = tid & 1;
  int la = lane & 15, lkq = lane >> 4;

  // stage B (WvT 128x128 bf16) once
#pragma unroll
  for (int q = 0; q < 8; ++q) {
    bf16x8 v = *(const bf16x8*)(WvT + (size_t)r * 128 + h * 64 + q * 8);
    *(bf16x8*)(Bs + r * 136 + h * 64 + q * 8) = v;
  }

  f32x4 acc[4][4];
#pragma unroll
  for (int i = 0; i < 4; ++i)
#pragma unroll
    for (int j = 0; j < 4; ++j) acc[i][j] = (f32x4)(0.f);

  for (int ks = 0; ks < 4; ++ks) {
    int k0 = ks * 32;
    const float* ap = sf + (m0 + r) * 128 + k0 + h * 16;
    float4 v0 = *(const float4*)(ap);
    float4 v1 = *(const float4*)(ap + 4);
    float4 v2 = *(const float4*)(ap + 8);
    float4 v3 = *(const float4*)(ap + 12);
    ushort4 p0 = make_ushort4(f2bf(v0.x), f2bf(v0.y), f2bf(v0.z), f2bf(v0.w));
    ushort4 p1 = make_ushort4(f2bf(v1.x), f2bf(v1.y), f2bf(v1.z), f2bf(v1.w));
    ushort4 p2 = make_ushort4(f2bf(v2.x), f2bf(v2.y), f2bf(v2.z), f2bf(v2.w));
    ushort4 p3 = make_ushort4(f2bf(v3.x), f2bf(v3.y), f2bf(v3.z), f2bf(v3.w));
    *(ushort4*)(As + r * 40 + h * 16)      = p0;
    *(ushort4*)(As + r * 40 + h * 16 + 4)  = p1;
    *(ushort4*)(As + r * 40 + h * 16 + 8)  = p2;
    *(ushort4*)(As + r * 40 + h * 16 + 12) = p3;
    __syncthreads();
    bf16x8 af[4], bf[4];
#pragma unroll
    for (int mi = 0; mi < 4; ++mi)
      af[mi] = *(const bf16x8*)(As + (wr * 64 + mi * 16 + la) * 40 + lkq * 8);
#pragma unroll
    for (int ni = 0; ni < 4; ++ni)
      bf[ni] = *(const bf16x8*)(Bs + (wc * 64 + ni * 16 + la) * 136 + k0 + lkq * 8);
#pragma unroll
    for (int mi = 0; mi < 4; ++mi)
#pragma unroll
      for (int ni = 0; ni < 4; ++ni)
        acc[mi][ni] = __builtin_amdgcn_mfma_f32_16x16x32_bf16(af[mi], bf[ni], acc[mi][ni], 0, 0, 0);
    __syncthreads();
  }

#pragma unroll
  for (int mi = 0; mi < 4; ++mi) {
#pragma unroll
    for (int ni = 0; ni < 4; ++ni) {
      int colg = wc * 64 + ni * 16 + la;
      float bb = bv[colg];
#pragma unroll
      for (int j = 0; j < 4; ++j) {
        size_t rowg = m0 + wr * 64 + mi * 16 + lkq * 4 + j;
        vm[rowg * 128 + colg] = acc[mi][ni][j] + bb;
      }
    }
  }
}

// One block per b: logits (dot of query with 8 masked keys), where(==0), softmax.
__global__ void attn_kernel(const float* __restrict__ query, const float* __restrict__ km,
                            float* __restrict__ logits, float* __restrict__ wts) {
  int b = blockIdx.x;
  int tid = threadIdx.x;
  int w = tid >> 6, lane = tid & 63;
  __shared__ float lg[8];
  __shared__ float post[8];
  __shared__ float ex[8];
  for (int n = w; n < 8; n += 4) {
    float p = 0.f;
    for (int k = lane; k < 384; k += 64)
      p += query[(size_t)b * 384 + k] * km[((size_t)b * 8 + n) * 384 + k];
    p = wave_sum(p);
    if (lane == 0) lg[n] = p * 0.08838834764831845f;  // 1/sqrt(128)
  }
  __syncthreads();
  if (tid < 8) {
    float l = lg[tid];
    l = (l == 0.0f) ? -1e9f : l;
    post[tid] = l;
    logits[(size_t)b * 8 + tid] = l;
  }
  __syncthreads();
  if (tid < 8) {
    float m = post[0];
#pragma unroll
    for (int i = 1; i < 8; ++i) m = fmaxf(m, post[i]);
    ex[tid] = expf(post[tid] - m);
  }
  __syncthreads();
  if (tid < 8) {
    float s = 0.f;
#pragma unroll
    for (int i = 0; i < 8; ++i) s += ex[i];
    wts[(size_t)b * 8 + tid] = ex[tid] / s;
  }
}

// One block per b: attended_sf = sum_n w_n * vm[b,n,:,:]; q_1 = task0 . attended rows.
__global__ void attend_kernel(const float* __restrict__ wts, const float* __restrict__ vm,
                              const float* __restrict__ task,
                              float* __restrict__ att, float* __restrict__ q1) {
  int b = blockIdx.x;
  int tid = threadIdx.x;
  __shared__ float attL[2048];
  float w[8];
#pragma unroll
  for (int n = 0; n < 8; ++n) w[n] = wts[(size_t)b * 8 + n];
#pragma unroll
  for (int i = 0; i < 8; ++i) {
    int idx = tid + i * 256;
    float a = 0.f;
#pragma unroll
    for (int n = 0; n < 8; ++n) a = fmaf(w[n], vm[((size_t)b * 8 + n) * 2048 + idx], a);
    att[(size_t)b * 2048 + idx] = a;
    attL[idx] = a;
  }
  __syncthreads();
  int wv = tid >> 6, lane = tid & 63;
  for (int j = wv; j < 16; j += 4) {
    float p = task[(size_t)b * 1024 + lane] * attL[j * 128 + lane]
            + task[(size_t)b * 1024 + 64 + lane] * attL[j * 128 + 64 + lane];
    p = wave_sum(p);
    if (lane == 0) q1[(size_t)b * 16 + j] = p;
  }
}

extern "C" void kernel_launch(void* const* d_in, const int* in_sizes, int n_in,
                              void* d_out, int out_size, void* d_ws, size_t ws_size,
                              hipStream_t stream) {
  const float* basis = (const float*)d_in[0];
  const float* sf    = (const float*)d_in[1];
  const float* task  = (const float*)d_in[2];
  const float* mask  = (const float*)d_in[3];
  const float* Wq    = (const float*)d_in[4];
  const float* Wk    = (const float*)d_in[5];
  const float* bk    = (const float*)d_in[6];
  const float* Wv    = (const float*)d_in[7];
  const float* bv    = (const float*)d_in[8];

  float* out  = (float*)d_out;
  float* q1   = out;
  float* att  = out + OFF_ATT;
  float* logi = out + OFF_LOG;
  float* wts  = out + OFF_W;
  float* km   = out + OFF_KM;
  float* vm   = out + OFF_VM;
  float* simo = out + OFF_SIM;

  // Stash plan (all regions rewritten by later kernels before validation):
  //  - Abf (bf16 131072x2304 = 604MB) lives in the vm region (1GB), consumed by
  //    qk_gemm before v_gemm overwrites vm.
  //  - query (f32 16384x384), invn, WkT/WqT/WvT (bf16) live in the att region
  //    (128MB), overwritten only by the final attend_kernel.
  float* query = att;                                   // 6,291,456 f32
  float* invn  = att + 6291456;                         //   131,072 f32
  unsigned short* WkT = (unsigned short*)(att + 6422528);   // 884,736 bf16
  unsigned short* WqT = WkT + 884736;                       // 884,736 bf16
  unsigned short* WvT = WqT + 884736;                       //  16,384 bf16
  unsigned short* Abf = (unsigned short*)vm;                // 301,989,888 bf16

  norm_kernel<<<32768, 256, 0, stream>>>(task, invn, simo);
  wprep_kernel<<<776, 256, 0, stream>>>(Wk, Wq, Wv, WkT, WqT, WvT);
  abuild_sim_kernel<<<16384, 256, 0, stream>>>(basis, sf, task, invn, Abf, simo);
  // keys: M=131072, N=384 (3 n-tiles), K=2304; bias + mask
  qk_gemm<0><<<3072, 256, 0, stream>>>(Abf, WkT, bk, mask, km);
  // query: M=16384 (Abf rows stride 8), N=384, K=2304
  qk_gemm<1><<<384, 256, 0, stream>>>(Abf, WqT, nullptr, nullptr, query);
  // values: M=2,097,152, N=128, K=128 (overwrites the Abf stash)
  v_gemm<<<16384, 256, 0, stream>>>(sf, WvT, bv, vm);
  attn_kernel<<<16384, 256, 0, stream>>>(query, km, logi, wts);
  attend_kernel<<<16384, 256, 0, stream>>>(wts, vm, task, att, q1);
}

// Round 4
// 1448.114 us; speedup vs baseline: 5.3034x; 1.9412x over previous
//
#include <hip/hip_runtime.h>
#include <hip/hip_bf16.h>
#include <math.h>

// B=16384, NB=8, NA=16, D=128, IN_DIM=2304, QK_DIM=384, V_DIM=128
static constexpr size_t OFF_ATT = 262144;      // attended_sf (33,554,432 f32)
static constexpr size_t OFF_LOG = 33816576;    // attn_logits
static constexpr size_t OFF_W   = 33947648;    // attention_weights
static constexpr size_t OFF_KM  = 34078720;    // keys_masked
static constexpr size_t OFF_VM  = 84410368;    // values_masked (268,435,456 f32)
static constexpr size_t OFF_SIM = 352845824;   // sim (7)

typedef short bf16x8 __attribute__((ext_vector_type(8)));
typedef float f32x4 __attribute__((ext_vector_type(4)));

__device__ inline unsigned short f2bf(float f) {
  union { float f; unsigned u; } x; x.f = f;
  unsigned r = x.u + 0x7FFFu + ((x.u >> 16) & 1u);  // RNE
  return (unsigned short)(r >> 16);
}

__device__ inline float wave_sum(float v) {
#pragma unroll
  for (int o = 32; o > 0; o >>= 1) v += __shfl_xor(v, o, 64);
  return v;
}

// One wave per (b,n) row: inverse L2 norm of task rows. Also zero sim slots.
__global__ void norm_kernel(const float* __restrict__ task, float* __restrict__ invn,
                            float* __restrict__ simo) {
  int idx = blockIdx.x * 4 + (threadIdx.x >> 6);
  int lane = threadIdx.x & 63;
  float t0 = task[(size_t)idx * 128 + lane];
  float t1 = task[(size_t)idx * 128 + 64 + lane];
  float s = wave_sum(t0 * t0 + t1 * t1);
  if (lane == 0) invn[idx] = rsqrtf(s);
  if (blockIdx.x == 0 && threadIdx.x < 7) simo[threadIdx.x] = 0.0f;
}

// Tiled transpose+cvt: WT[n][k] = bf16(W[k][n]). 64x64 tiles, coalesced both sides.
__global__ void wprep_t(const float* __restrict__ W, unsigned short* __restrict__ WT,
                        int K, int N) {
  int ntn = N >> 6;
  int kt = blockIdx.x / ntn, nt = blockIdx.x % ntn;
  int k0 = kt * 64, n0 = nt * 64;
  __shared__ float t[64][65];
  int tid = threadIdx.x;
  int r = tid >> 2, c0 = (tid & 3) * 16;
#pragma unroll
  for (int q = 0; q < 4; ++q) {
    float4 v = *(const float4*)(W + (size_t)(k0 + r) * N + n0 + c0 + q * 4);
    t[r][c0 + q * 4 + 0] = v.x; t[r][c0 + q * 4 + 1] = v.y;
    t[r][c0 + q * 4 + 2] = v.z; t[r][c0 + q * 4 + 3] = v.w;
  }
  __syncthreads();
  int n = tid >> 2, kc0 = (tid & 3) * 16;
#pragma unroll
  for (int q = 0; q < 4; ++q) {
    int kc = kc0 + q * 4;
    ushort4 o = make_ushort4(f2bf(t[kc + 0][n]), f2bf(t[kc + 1][n]),
                             f2bf(t[kc + 2][n]), f2bf(t[kc + 3][n]));
    *(ushort4*)(WT + (size_t)(n0 + n) * K + k0 + kc) = o;
  }
}

// One block (576 thr) per b: thread owns one float4-chunk f of the 2304-row.
// Loads all 8 rows' chunks (independent, deep MLP), writes bf16 Abf, and
// accumulates the 7 consecutive-row squared-diff partials in registers.
__global__ __launch_bounds__(576) void abuild_sim(const float* __restrict__ basis,
                                                  const float* __restrict__ sf,
                                                  const float* __restrict__ task,
                                                  const float* __restrict__ invn,
                                                  unsigned short* __restrict__ Abf,
                                                  float* __restrict__ simo) {
  int b = blockIdx.x;
  int f = threadIdx.x;  // 0..575
  size_t row0 = (size_t)b * 8;
  float4 v[8];
#pragma unroll
  for (int n = 0; n < 8; ++n) {
    size_t row = row0 + n;
    float4 x;
    if (f < 32)       x = *(const float4*)(basis + row * 128 + f * 4);
    else if (f < 544) x = *(const float4*)(sf + row * 2048 + (f - 32) * 4);
    else {
      x = *(const float4*)(task + row * 128 + (f - 544) * 4);
      float s = invn[row];
      x.x *= s; x.y *= s; x.z *= s; x.w *= s;
    }
    v[n] = x;
    ushort4 o = make_ushort4(f2bf(x.x), f2bf(x.y), f2bf(x.z), f2bf(x.w));
    *(ushort4*)(Abf + row * 2304 + f * 4) = o;
  }
  float s7[7];
#pragma unroll
  for (int n = 1; n < 8; ++n) {
    float dx = v[n].x - v[n - 1].x, dy = v[n].y - v[n - 1].y;
    float dz = v[n].z - v[n - 1].z, dw = v[n].w - v[n - 1].w;
    s7[n - 1] = dx * dx + dy * dy + dz * dz + dw * dw;
  }
  __shared__ float red[9][7];
  int wid = threadIdx.x >> 6, lane = threadIdx.x & 63;
#pragma unroll
  for (int i = 0; i < 7; ++i) {
    float p = wave_sum(s7[i]);
    if (lane == 0) red[wid][i] = p;
  }
  __syncthreads();
  if (threadIdx.x < 7) {
    float s = 0.f;
#pragma unroll
    for (int w = 0; w < 9; ++w) s += red[w][threadIdx.x];
    atomicAdd(&simo[threadIdx.x], expf(-0.5f * s) * (1.0f / 16384.0f));
  }
}

// MFMA GEMM for keys (MODE 0) / query (MODE 1): out[M x 384] = Abf rows @ WT^T.
// 128x128 tile, BK=32, 4 waves (2x2 of 64x64), 2-phase register prefetch.
template <int MODE>
__global__ __launch_bounds__(256) void qk_gemm(const unsigned short* __restrict__ Abf,
                                               const unsigned short* __restrict__ WT,
                                               const float* __restrict__ bias,
                                               const float* __restrict__ mask,
                                               float* __restrict__ outp) {
  __shared__ unsigned short As[128 * 40];
  __shared__ unsigned short Bs[128 * 40];
  int nwg = gridDim.x, per = nwg >> 3;
  int bid = blockIdx.x;
  int swz = (bid & 7) * per + (bid >> 3);
  int mt = swz / 3, nt = swz - mt * 3;
  int tid = threadIdx.x;
  int wave = tid >> 6, lane = tid & 63;
  int wr = wave >> 1, wc = wave & 1;
  int r = tid >> 1, h = tid & 1;

  f32x4 acc[4][4];
#pragma unroll
  for (int i = 0; i < 4; ++i)
#pragma unroll
    for (int j = 0; j < 4; ++j) acc[i][j] = (f32x4)(0.f);

  size_t arow = (MODE == 1) ? (size_t)(mt * 128 + r) * 8 : (size_t)(mt * 128 + r);
  const unsigned short* aptr = Abf + arow * 2304 + h * 16;
  const unsigned short* bptr = WT + (size_t)(nt * 128 + r) * 2304 + h * 16;
  int la = lane & 15, lk = (lane >> 4) * 8;

  bf16x8 a0 = *(const bf16x8*)(aptr);
  bf16x8 a1 = *(const bf16x8*)(aptr + 8);
  bf16x8 b0 = *(const bf16x8*)(bptr);
  bf16x8 b1 = *(const bf16x8*)(bptr + 8);

  for (int ks = 0; ks < 72; ++ks) {
    *(bf16x8*)(As + r * 40 + h * 16)     = a0;
    *(bf16x8*)(As + r * 40 + h * 16 + 8) = a1;
    *(bf16x8*)(Bs + r * 40 + h * 16)     = b0;
    *(bf16x8*)(Bs + r * 40 + h * 16 + 8) = b1;
    __syncthreads();
    if (ks < 71) {  // prefetch next tile into registers; latency hides under MFMA
      int k1 = (ks + 1) * 32;
      a0 = *(const bf16x8*)(aptr + k1);
      a1 = *(const bf16x8*)(aptr + k1 + 8);
      b0 = *(const bf16x8*)(bptr + k1);
      b1 = *(const bf16x8*)(bptr + k1 + 8);
    }
    bf16x8 af[4], bf[4];
#pragma unroll
    for (int mi = 0; mi < 4; ++mi)
      af[mi] = *(const bf16x8*)(As + (wr * 64 + mi * 16 + la) * 40 + lk);
#pragma unroll
    for (int ni = 0; ni < 4; ++ni)
      bf[ni] = *(const bf16x8*)(Bs + (wc * 64 + ni * 16 + la) * 40 + lk);
#pragma unroll
    for (int mi = 0; mi < 4; ++mi)
#pragma unroll
      for (int ni = 0; ni < 4; ++ni)
        acc[mi][ni] = __builtin_amdgcn_mfma_f32_16x16x32_bf16(af[mi], bf[ni], acc[mi][ni], 0, 0, 0);
    __syncthreads();
  }

  int rq = lane >> 4;
#pragma unroll
  for (int mi = 0; mi < 4; ++mi) {
#pragma unroll
    for (int ni = 0; ni < 4; ++ni) {
      int colg = nt * 128 + wc * 64 + ni * 16 + la;
#pragma unroll
      for (int j = 0; j < 4; ++j) {
        int rowg = mt * 128 + wr * 64 + mi * 16 + rq * 4 + j;
        float v = acc[mi][ni][j];
        if (MODE == 0)
          v = (v + bias[colg]) * mask[(size_t)rowg * 128 + (unsigned)colg / 3u];
        outp[(size_t)rowg * 384 + colg] = v;
      }
    }
  }
}

// One block per b: logits (dot of query with 8 masked keys), where(==0), softmax.
__global__ void attn_kernel(const float* __restrict__ query, const float* __restrict__ km,
                            float* __restrict__ logits, float* __restrict__ wts) {
  int b = blockIdx.x;
  int tid = threadIdx.x;
  int w = tid >> 6, lane = tid & 63;
  __shared__ float lg[8];
  __shared__ float post[8];
  __shared__ float ex[8];
  for (int n = w; n < 8; n += 4) {
    float p = 0.f;
    for (int k = lane; k < 384; k += 64)
      p += query[(size_t)b * 384 + k] * km[((size_t)b * 8 + n) * 384 + k];
    p = wave_sum(p);
    if (lane == 0) lg[n] = p * 0.08838834764831845f;  // 1/sqrt(128)
  }
  __syncthreads();
  if (tid < 8) {
    float l = lg[tid];
    l = (l == 0.0f) ? -1e9f : l;
    post[tid] = l;
    logits[(size_t)b * 8 + tid] = l;
  }
  __syncthreads();
  if (tid < 8) {
    float m = post[0];
#pragma unroll
    for (int i = 1; i < 8; ++i) m = fmaxf(m, post[i]);
    ex[tid] = expf(post[tid] - m);
  }
  __syncthreads();
  if (tid < 8) {
    float s = 0.f;
#pragma unroll
    for (int i = 0; i < 8; ++i) s += ex[i];
    wts[(size_t)b * 8 + tid] = ex[tid] / s;
  }
}

// Values GEMM + fused attend + q1. One block = one b (rows (b,n,a), all 8n x 16a).
// vm = sf @ Wv + bv; attended[a][d] = sum_n w[n]*vm; q1[j] = sum_d task0[d]*attended[j][d].
// Wv (f32, input) is transposed+converted to bf16 in LDS at block start — no
// global stash, so no cross-block lifetime hazard (round-3 bug).
__global__ __launch_bounds__(256) void v_gemm_attend(const float* __restrict__ sf,
                                                     const float* __restrict__ Wv,
                                                     const float* __restrict__ bv,
                                                     const float* __restrict__ wts,
                                                     const float* __restrict__ task,
                                                     float* __restrict__ vm,
                                                     float* __restrict__ att,
                                                     float* __restrict__ q1) {
  __shared__ unsigned short As[128 * 40];   // also reused as attL (f32 16x132) in epilogue
  __shared__ unsigned short Bs[128 * 136];
  float* attL = (float*)As;                 // 16*132*4 = 8448B <= 10240B
  int bid = blockIdx.x;
  int swz = (bid & 7) * 2048 + (bid >> 3);
  int b = swz;
  size_t m0 = (size_t)swz * 128;
  int tid = threadIdx.x;
  int wave = tid >> 6, lane = tid & 63;
  int wr = wave >> 1, wc = wave & 1;
  int r = tid >> 1, h = tid & 1;
  int la = lane & 15, lkq = lane >> 4;

  // stage B: Bs[n][k] = bf16(Wv[k][n]); coalesced f32 reads, scattered b16 LDS writes
#pragma unroll
  for (int q = 0; q < 16; ++q) {
    int flat = q * 256 + tid;         // 0..4095
    int k = flat >> 5;                // 0..127
    int n4 = (flat & 31) * 4;         // 0,4,..,124
    float4 v = *(const float4*)(Wv + (size_t)k * 128 + n4);
    Bs[(n4 + 0) * 136 + k] = f2bf(v.x);
    Bs[(n4 + 1) * 136 + k] = f2bf(v.y);
    Bs[(n4 + 2) * 136 + k] = f2bf(v.z);
    Bs[(n4 + 3) * 136 + k] = f2bf(v.w);
  }

  f32x4 acc[4][4];
#pragma unroll
  for (int i = 0; i < 4; ++i)
#pragma unroll
    for (int j = 0; j < 4; ++j) acc[i][j] = (f32x4)(0.f);

  for (int ks = 0; ks < 4; ++ks) {
    int k0 = ks * 32;
    const float* ap = sf + (m0 + r) * 128 + k0 + h * 16;
    float4 v0 = *(const float4*)(ap);
    float4 v1 = *(const float4*)(ap + 4);
    float4 v2 = *(const float4*)(ap + 8);
    float4 v3 = *(const float4*)(ap + 12);
    ushort4 p0 = make_ushort4(f2bf(v0.x), f2bf(v0.y), f2bf(v0.z), f2bf(v0.w));
    ushort4 p1 = make_ushort4(f2bf(v1.x), f2bf(v1.y), f2bf(v1.z), f2bf(v1.w));
    ushort4 p2 = make_ushort4(f2bf(v2.x), f2bf(v2.y), f2bf(v2.z), f2bf(v2.w));
    ushort4 p3 = make_ushort4(f2bf(v3.x), f2bf(v3.y), f2bf(v3.z), f2bf(v3.w));
    *(ushort4*)(As + r * 40 + h * 16)      = p0;
    *(ushort4*)(As + r * 40 + h * 16 + 4)  = p1;
    *(ushort4*)(As + r * 40 + h * 16 + 8)  = p2;
    *(ushort4*)(As + r * 40 + h * 16 + 12) = p3;
    __syncthreads();
    bf16x8 af[4], bfr[4];
#pragma unroll
    for (int mi = 0; mi < 4; ++mi)
      af[mi] = *(const bf16x8*)(As + (wr * 64 + mi * 16 + la) * 40 + lkq * 8);
#pragma unroll
    for (int ni = 0; ni < 4; ++ni)
      bfr[ni] = *(const bf16x8*)(Bs + (wc * 64 + ni * 16 + la) * 136 + k0 + lkq * 8);
#pragma unroll
    for (int mi = 0; mi < 4; ++mi)
#pragma unroll
      for (int ni = 0; ni < 4; ++ni)
        acc[mi][ni] = __builtin_amdgcn_mfma_f32_16x16x32_bf16(af[mi], bfr[ni], acc[mi][ni], 0, 0, 0);
    __syncthreads();
  }

  // epilogue: vm write + weighted partials over mi (n = wr*4+mi)
  float w4[4];
#pragma unroll
  for (int mi = 0; mi < 4; ++mi) w4[mi] = wts[(size_t)b * 8 + wr * 4 + mi];
  float pacc[4][4];  // [ni][j]
#pragma unroll
  for (int ni = 0; ni < 4; ++ni)
#pragma unroll
    for (int j = 0; j < 4; ++j) pacc[ni][j] = 0.f;
#pragma unroll
  for (int mi = 0; mi < 4; ++mi) {
#pragma unroll
    for (int ni = 0; ni < 4; ++ni) {
      int colg = wc * 64 + ni * 16 + la;
      float bb = bv[colg];
#pragma unroll
      for (int j = 0; j < 4; ++j) {
        size_t rowg = m0 + wr * 64 + mi * 16 + lkq * 4 + j;
        float v = acc[mi][ni][j] + bb;
        vm[rowg * 128 + colg] = v;
        pacc[ni][j] = fmaf(w4[mi], v, pacc[ni][j]);
      }
    }
  }
  // cross-wave (wr) reduce into attL[a][col], a = lkq*4+j
  if (wr == 0) {
#pragma unroll
    for (int ni = 0; ni < 4; ++ni)
#pragma unroll
      for (int j = 0; j < 4; ++j)
        attL[(lkq * 4 + j) * 132 + wc * 64 + ni * 16 + la] = pacc[ni][j];
  }
  __syncthreads();
  if (wr == 1) {
#pragma unroll
    for (int ni = 0; ni < 4; ++ni)
#pragma unroll
      for (int j = 0; j < 4; ++j)
        attL[(lkq * 4 + j) * 132 + wc * 64 + ni * 16 + la] += pacc[ni][j];
  }
  __syncthreads();
  // write attended (2048 f32) + q1 (16)
#pragma unroll
  for (int i = 0; i < 2; ++i) {
    int fidx = tid + i * 256;
    int a = fidx >> 5, c = (fidx & 31) * 4;
    f32x4 vv = *(const f32x4*)(attL + a * 132 + c);
    *(f32x4*)(att + (size_t)b * 2048 + a * 128 + c) = vv;
  }
  for (int j = wave; j < 16; j += 4) {
    float p = task[(size_t)b * 1024 + lane] * attL[j * 132 + lane]
            + task[(size_t)b * 1024 + 64 + lane] * attL[j * 132 + 64 + lane];
    p = wave_sum(p);
    if (lane == 0) q1[(size_t)b * 16 + j] = p;
  }
}

extern "C" void kernel_launch(void* const* d_in, const int* in_sizes, int n_in,
                              void* d_out, int out_size, void* d_ws, size_t ws_size,
                              hipStream_t stream) {
  const float* basis = (const float*)d_in[0];
  const float* sf    = (const float*)d_in[1];
  const float* task  = (const float*)d_in[2];
  const float* mask  = (const float*)d_in[3];
  const float* Wq    = (const float*)d_in[4];
  const float* Wk    = (const float*)d_in[5];
  const float* bk    = (const float*)d_in[6];
  const float* Wv    = (const float*)d_in[7];
  const float* bv    = (const float*)d_in[8];

  float* out  = (float*)d_out;
  float* q1   = out;
  float* att  = out + OFF_ATT;
  float* logi = out + OFF_LOG;
  float* wts  = out + OFF_W;
  float* km   = out + OFF_KM;
  float* vm   = out + OFF_VM;
  float* simo = out + OFF_SIM;

  // Stash plan (every stash is consumed by kernels that COMPLETE before the
  // kernel that overwrites its region launches — stream-ordered, no intra-kernel
  // read/write overlap):
  //  - Abf (bf16 131072x2304 = 604MB) in the vm region (1GB); consumed by the
  //    qk_gemms, both of which finish before v_gemm_attend (which writes vm).
  //  - query/invn/WkT/WqT in the att region; query consumed by attn_kernel,
  //    invn by norm/abuild, WkT/WqT by the qk_gemms — all before v_gemm_attend
  //    (the only writer of att) launches. Wv is NOT stashed (round-3 race);
  //    v_gemm_attend stages it from the immutable input directly.
  float* query = att;                                       // 6,291,456 f32
  float* invn  = att + 6291456;                             //   131,072 f32
  unsigned short* WkT = (unsigned short*)(att + 6422528);   //   884,736 bf16
  unsigned short* WqT = WkT + 884736;                       //   884,736 bf16
  unsigned short* Abf = (unsigned short*)vm;                // 301,989,888 bf16

  norm_kernel<<<32768, 256, 0, stream>>>(task, invn, simo);
  wprep_t<<<216, 256, 0, stream>>>(Wk, WkT, 2304, 384);
  wprep_t<<<216, 256, 0, stream>>>(Wq, WqT, 2304, 384);
  abuild_sim<<<16384, 576, 0, stream>>>(basis, sf, task, invn, Abf, simo);
  // keys: M=131072, N=384 (3 n-tiles), K=2304; bias + mask
  qk_gemm<0><<<3072, 256, 0, stream>>>(Abf, WkT, bk, mask, km);
  // query: M=16384 (Abf rows stride 8), N=384, K=2304
  qk_gemm<1><<<384, 256, 0, stream>>>(Abf, WqT, nullptr, nullptr, query);
  attn_kernel<<<16384, 256, 0, stream>>>(query, km, logi, wts);
  // values GEMM + fused attend/q1: M=2,097,152, N=128, K=128 (overwrites Abf stash)
  v_gemm_attend<<<16384, 256, 0, stream>>>(sf, Wv, bv, wts, task, vm, att, q1);
}

// Round 5
// 1401.139 us; speedup vs baseline: 5.4812x; 1.0335x over previous
//
#include <hip/hip_runtime.h>
#include <hip/hip_bf16.h>
#include <math.h>

// B=16384, NB=8, NA=16, D=128, IN_DIM=2304, QK_DIM=384, V_DIM=128
static constexpr size_t OFF_ATT = 262144;      // attended_sf (33,554,432 f32)
static constexpr size_t OFF_LOG = 33816576;    // attn_logits
static constexpr size_t OFF_W   = 33947648;    // attention_weights
static constexpr size_t OFF_KM  = 34078720;    // keys_masked
static constexpr size_t OFF_VM  = 84410368;    // values_masked (268,435,456 f32)
static constexpr size_t OFF_SIM = 352845824;   // sim (7)

typedef short bf16x8 __attribute__((ext_vector_type(8)));
typedef float f32x4 __attribute__((ext_vector_type(4)));

__device__ inline unsigned short f2bf(float f) {
  union { float f; unsigned u; } x; x.f = f;
  unsigned r = x.u + 0x7FFFu + ((x.u >> 16) & 1u);  // RNE
  return (unsigned short)(r >> 16);
}

__device__ inline float wave_sum(float v) {
#pragma unroll
  for (int o = 32; o > 0; o >>= 1) v += __shfl_xor(v, o, 64);
  return v;
}

// One wave per (b,n) row: inverse L2 norm of task rows. Also zero sim slots.
__global__ void norm_kernel(const float* __restrict__ task, float* __restrict__ invn,
                            float* __restrict__ simo) {
  int idx = blockIdx.x * 4 + (threadIdx.x >> 6);
  int lane = threadIdx.x & 63;
  float t0 = task[(size_t)idx * 128 + lane];
  float t1 = task[(size_t)idx * 128 + 64 + lane];
  float s = wave_sum(t0 * t0 + t1 * t1);
  if (lane == 0) invn[idx] = rsqrtf(s);
  if (blockIdx.x == 0 && threadIdx.x < 7) simo[threadIdx.x] = 0.0f;
}

// Tiled transpose+cvt: WT[n][k] = bf16(W[k][n]). 64x64 tiles, coalesced both sides.
__global__ void wprep_t(const float* __restrict__ W, unsigned short* __restrict__ WT,
                        int K, int N) {
  int ntn = N >> 6;
  int kt = blockIdx.x / ntn, nt = blockIdx.x % ntn;
  int k0 = kt * 64, n0 = nt * 64;
  __shared__ float t[64][65];
  int tid = threadIdx.x;
  int r = tid >> 2, c0 = (tid & 3) * 16;
#pragma unroll
  for (int q = 0; q < 4; ++q) {
    float4 v = *(const float4*)(W + (size_t)(k0 + r) * N + n0 + c0 + q * 4);
    t[r][c0 + q * 4 + 0] = v.x; t[r][c0 + q * 4 + 1] = v.y;
    t[r][c0 + q * 4 + 2] = v.z; t[r][c0 + q * 4 + 3] = v.w;
  }
  __syncthreads();
  int n = tid >> 2, kc0 = (tid & 3) * 16;
#pragma unroll
  for (int q = 0; q < 4; ++q) {
    int kc = kc0 + q * 4;
    ushort4 o = make_ushort4(f2bf(t[kc + 0][n]), f2bf(t[kc + 1][n]),
                             f2bf(t[kc + 2][n]), f2bf(t[kc + 3][n]));
    *(ushort4*)(WT + (size_t)(n0 + n) * K + k0 + kc) = o;
  }
}

// One block (576 thr) per b: thread owns one float4-chunk f of the 2304-row.
// Loads all 8 rows' chunks (independent), writes bf16 Abf, and accumulates the
// 7 consecutive-row squared-diff partials in registers.
__global__ __launch_bounds__(576) void abuild_sim(const float* __restrict__ basis,
                                                  const float* __restrict__ sf,
                                                  const float* __restrict__ task,
                                                  const float* __restrict__ invn,
                                                  unsigned short* __restrict__ Abf,
                                                  float* __restrict__ simo) {
  int b = blockIdx.x;
  int f = threadIdx.x;  // 0..575
  size_t row0 = (size_t)b * 8;
  float4 v[8];
#pragma unroll
  for (int n = 0; n < 8; ++n) {
    size_t row = row0 + n;
    float4 x;
    if (f < 32)       x = *(const float4*)(basis + row * 128 + f * 4);
    else if (f < 544) x = *(const float4*)(sf + row * 2048 + (f - 32) * 4);
    else {
      x = *(const float4*)(task + row * 128 + (f - 544) * 4);
      float s = invn[row];
      x.x *= s; x.y *= s; x.z *= s; x.w *= s;
    }
    v[n] = x;
    ushort4 o = make_ushort4(f2bf(x.x), f2bf(x.y), f2bf(x.z), f2bf(x.w));
    *(ushort4*)(Abf + row * 2304 + f * 4) = o;
  }
  float s7[7];
#pragma unroll
  for (int n = 1; n < 8; ++n) {
    float dx = v[n].x - v[n - 1].x, dy = v[n].y - v[n - 1].y;
    float dz = v[n].z - v[n - 1].z, dw = v[n].w - v[n - 1].w;
    s7[n - 1] = dx * dx + dy * dy + dz * dz + dw * dw;
  }
  __shared__ float red[9][7];
  int wid = threadIdx.x >> 6, lane = threadIdx.x & 63;
#pragma unroll
  for (int i = 0; i < 7; ++i) {
    float p = wave_sum(s7[i]);
    if (lane == 0) red[wid][i] = p;
  }
  __syncthreads();
  if (threadIdx.x < 7) {
    float s = 0.f;
#pragma unroll
    for (int w = 0; w < 9; ++w) s += red[w][threadIdx.x];
    atomicAdd(&simo[threadIdx.x], expf(-0.5f * s) * (1.0f / 16384.0f));
  }
}

// MFMA GEMM for keys (MODE 0) / query (MODE 1): out[M x 384] = Abf rows @ WT^T.
// 128x128 tile, BK=32, 4 waves (2x2 of 64x64). global_load_lds (16B) staging into
// double-buffered linear LDS [128][32] bf16 (m97 structure, ~874 TF class).
template <int MODE>
__global__ __launch_bounds__(256) void qk_gemm(const unsigned short* __restrict__ Abf,
                                               const unsigned short* __restrict__ WT,
                                               const float* __restrict__ bias,
                                               const float* __restrict__ mask,
                                               float* __restrict__ outp) {
  __shared__ unsigned short As[2 * 4096];
  __shared__ unsigned short Bs[2 * 4096];
  int nwg = gridDim.x, per = nwg >> 3;
  int bid = blockIdx.x;
  int swz = (bid & 7) * per + (bid >> 3);
  int mt = swz / 3, nt = swz - mt * 3;
  int tid = threadIdx.x;
  int wave = tid >> 6, lane = tid & 63;
  int wr = wave >> 1, wc = wave & 1;
  int m0g = mt * 128, n0g = nt * 128;

  // staging geometry: chunk c = (wave*2+q)*64 + lane; row = c>>2, kc = (c&3)*8
  int c_lo = wave * 2 * 64 + lane;          // q=0 chunk index
  int row_q0 = c_lo >> 2, kc_q0 = (c_lo & 3) * 8;
  int c_hi = c_lo + 64;                     // q=1
  int row_q1 = c_hi >> 2, kc_q1 = (c_hi & 3) * 8;
  size_t ga_q0 = (MODE == 1) ? (size_t)(m0g + row_q0) * 8 : (size_t)(m0g + row_q0);
  size_t ga_q1 = (MODE == 1) ? (size_t)(m0g + row_q1) * 8 : (size_t)(m0g + row_q1);
  const unsigned short* ag0 = Abf + ga_q0 * 2304 + kc_q0;
  const unsigned short* ag1 = Abf + ga_q1 * 2304 + kc_q1;
  const unsigned short* bg0 = WT + (size_t)(n0g + row_q0) * 2304 + kc_q0;
  const unsigned short* bg1 = WT + (size_t)(n0g + row_q1) * 2304 + kc_q1;
  int ldsoff0 = wave * 2 * 512;             // elements; uniform per wave
  int ldsoff1 = ldsoff0 + 512;

#define STAGE(ks, cur)                                                                   \
  do {                                                                                   \
    int _k0 = (ks) * 32;                                                                 \
    unsigned short* _a = As + (cur) * 4096;                                              \
    unsigned short* _b = Bs + (cur) * 4096;                                              \
    __builtin_amdgcn_global_load_lds(                                                    \
        (const __attribute__((address_space(1))) void*)(ag0 + _k0),                      \
        (__attribute__((address_space(3))) void*)(_a + ldsoff0), 16, 0, 0);              \
    __builtin_amdgcn_global_load_lds(                                                    \
        (const __attribute__((address_space(1))) void*)(ag1 + _k0),                      \
        (__attribute__((address_space(3))) void*)(_a + ldsoff1), 16, 0, 0);              \
    __builtin_amdgcn_global_load_lds(                                                    \
        (const __attribute__((address_space(1))) void*)(bg0 + _k0),                      \
        (__attribute__((address_space(3))) void*)(_b + ldsoff0), 16, 0, 0);              \
    __builtin_amdgcn_global_load_lds(                                                    \
        (const __attribute__((address_space(1))) void*)(bg1 + _k0),                      \
        (__attribute__((address_space(3))) void*)(_b + ldsoff1), 16, 0, 0);              \
  } while (0)

  f32x4 acc[4][4];
#pragma unroll
  for (int i = 0; i < 4; ++i)
#pragma unroll
    for (int j = 0; j < 4; ++j) acc[i][j] = (f32x4)(0.f);

  int la = lane & 15, lk = (lane >> 4) * 8;

  STAGE(0, 0);
  __syncthreads();
  int cur = 0;
  for (int ks = 0; ks < 72; ++ks) {
    if (ks < 71) STAGE(ks + 1, cur ^ 1);   // prefetch overlaps ds_read+MFMA below
    const unsigned short* aL = As + cur * 4096;
    const unsigned short* bL = Bs + cur * 4096;
    bf16x8 af[4], bf[4];
#pragma unroll
    for (int mi = 0; mi < 4; ++mi)
      af[mi] = *(const bf16x8*)(aL + (wr * 64 + mi * 16 + la) * 32 + lk);
#pragma unroll
    for (int ni = 0; ni < 4; ++ni)
      bf[ni] = *(const bf16x8*)(bL + (wc * 64 + ni * 16 + la) * 32 + lk);
#pragma unroll
    for (int mi = 0; mi < 4; ++mi)
#pragma unroll
      for (int ni = 0; ni < 4; ++ni)
        acc[mi][ni] = __builtin_amdgcn_mfma_f32_16x16x32_bf16(af[mi], bf[ni], acc[mi][ni], 0, 0, 0);
    __syncthreads();
    cur ^= 1;
  }
#undef STAGE

  int rq = lane >> 4;
#pragma unroll
  for (int mi = 0; mi < 4; ++mi) {
#pragma unroll
    for (int ni = 0; ni < 4; ++ni) {
      int colg = nt * 128 + wc * 64 + ni * 16 + la;
#pragma unroll
      for (int j = 0; j < 4; ++j) {
        int rowg = mt * 128 + wr * 64 + mi * 16 + rq * 4 + j;
        float v = acc[mi][ni][j];
        if (MODE == 0)
          v = (v + bias[colg]) * mask[(size_t)rowg * 128 + (unsigned)colg / 3u];
        outp[(size_t)rowg * 384 + colg] = v;
      }
    }
  }
}

// One block per b: logits (dot of query with 8 masked keys), where(==0), softmax.
__global__ void attn_kernel(const float* __restrict__ query, const float* __restrict__ km,
                            float* __restrict__ logits, float* __restrict__ wts) {
  int b = blockIdx.x;
  int tid = threadIdx.x;
  int w = tid >> 6, lane = tid & 63;
  __shared__ float lg[8];
  __shared__ float post[8];
  __shared__ float ex[8];
  for (int n = w; n < 8; n += 4) {
    float p = 0.f;
    for (int k = lane; k < 384; k += 64)
      p += query[(size_t)b * 384 + k] * km[((size_t)b * 8 + n) * 384 + k];
    p = wave_sum(p);
    if (lane == 0) lg[n] = p * 0.08838834764831845f;  // 1/sqrt(128)
  }
  __syncthreads();
  if (tid < 8) {
    float l = lg[tid];
    l = (l == 0.0f) ? -1e9f : l;
    post[tid] = l;
    logits[(size_t)b * 8 + tid] = l;
  }
  __syncthreads();
  if (tid < 8) {
    float m = post[0];
#pragma unroll
    for (int i = 1; i < 8; ++i) m = fmaxf(m, post[i]);
    ex[tid] = expf(post[tid] - m);
  }
  __syncthreads();
  if (tid < 8) {
    float s = 0.f;
#pragma unroll
    for (int i = 0; i < 8; ++i) s += ex[i];
    wts[(size_t)b * 8 + tid] = ex[tid] / s;
  }
}

// Values GEMM + fused attend + q1. One block = one b (rows (b,n,a), all 8n x 16a).
// vm = sf @ Wv + bv; attended[a][d] = sum_n w[n]*vm; q1[j] = sum_d task0[d]*attended[j][d].
// Wv (f32, input) is transposed+converted to bf16 in LDS at block start — no
// global stash, so no cross-block lifetime hazard (round-3 bug).
__global__ __launch_bounds__(256) void v_gemm_attend(const float* __restrict__ sf,
                                                     const float* __restrict__ Wv,
                                                     const float* __restrict__ bv,
                                                     const float* __restrict__ wts,
                                                     const float* __restrict__ task,
                                                     float* __restrict__ vm,
                                                     float* __restrict__ att,
                                                     float* __restrict__ q1) {
  __shared__ unsigned short As[128 * 40];   // also reused as attL (f32 16x132) in epilogue
  __shared__ unsigned short Bs[128 * 136];
  float* attL = (float*)As;                 // 16*132*4 = 8448B <= 10240B
  int bid = blockIdx.x;
  int swz = (bid & 7) * 2048 + (bid >> 3);
  int b = swz;
  size_t m0 = (size_t)swz * 128;
  int tid = threadIdx.x;
  int wave = tid >> 6, lane = tid & 63;
  int wr = wave >> 1, wc = wave & 1;
  int r = tid >> 1, h = tid & 1;
  int la = lane & 15, lkq = lane >> 4;

  // stage B: Bs[n][k] = bf16(Wv[k][n]); coalesced f32 reads, scattered b16 LDS writes
#pragma unroll
  for (int q = 0; q < 16; ++q) {
    int flat = q * 256 + tid;         // 0..4095
    int k = flat >> 5;                // 0..127
    int n4 = (flat & 31) * 4;         // 0,4,..,124
    float4 v = *(const float4*)(Wv + (size_t)k * 128 + n4);
    Bs[(n4 + 0) * 136 + k] = f2bf(v.x);
    Bs[(n4 + 1) * 136 + k] = f2bf(v.y);
    Bs[(n4 + 2) * 136 + k] = f2bf(v.z);
    Bs[(n4 + 3) * 136 + k] = f2bf(v.w);
  }

  f32x4 acc[4][4];
#pragma unroll
  for (int i = 0; i < 4; ++i)
#pragma unroll
    for (int j = 0; j < 4; ++j) acc[i][j] = (f32x4)(0.f);

  for (int ks = 0; ks < 4; ++ks) {
    int k0 = ks * 32;
    const float* ap = sf + (m0 + r) * 128 + k0 + h * 16;
    float4 v0 = *(const float4*)(ap);
    float4 v1 = *(const float4*)(ap + 4);
    float4 v2 = *(const float4*)(ap + 8);
    float4 v3 = *(const float4*)(ap + 12);
    ushort4 p0 = make_ushort4(f2bf(v0.x), f2bf(v0.y), f2bf(v0.z), f2bf(v0.w));
    ushort4 p1 = make_ushort4(f2bf(v1.x), f2bf(v1.y), f2bf(v1.z), f2bf(v1.w));
    ushort4 p2 = make_ushort4(f2bf(v2.x), f2bf(v2.y), f2bf(v2.z), f2bf(v2.w));
    ushort4 p3 = make_ushort4(f2bf(v3.x), f2bf(v3.y), f2bf(v3.z), f2bf(v3.w));
    *(ushort4*)(As + r * 40 + h * 16)      = p0;
    *(ushort4*)(As + r * 40 + h * 16 + 4)  = p1;
    *(ushort4*)(As + r * 40 + h * 16 + 8)  = p2;
    *(ushort4*)(As + r * 40 + h * 16 + 12) = p3;
    __syncthreads();
    bf16x8 af[4], bfr[4];
#pragma unroll
    for (int mi = 0; mi < 4; ++mi)
      af[mi] = *(const bf16x8*)(As + (wr * 64 + mi * 16 + la) * 40 + lkq * 8);
#pragma unroll
    for (int ni = 0; ni < 4; ++ni)
      bfr[ni] = *(const bf16x8*)(Bs + (wc * 64 + ni * 16 + la) * 136 + k0 + lkq * 8);
#pragma unroll
    for (int mi = 0; mi < 4; ++mi)
#pragma unroll
      for (int ni = 0; ni < 4; ++ni)
        acc[mi][ni] = __builtin_amdgcn_mfma_f32_16x16x32_bf16(af[mi], bfr[ni], acc[mi][ni], 0, 0, 0);
    __syncthreads();
  }

  // epilogue: vm write + weighted partials over mi (n = wr*4+mi)
  float w4[4];
#pragma unroll
  for (int mi = 0; mi < 4; ++mi) w4[mi] = wts[(size_t)b * 8 + wr * 4 + mi];
  float pacc[4][4];  // [ni][j]
#pragma unroll
  for (int ni = 0; ni < 4; ++ni)
#pragma unroll
    for (int j = 0; j < 4; ++j) pacc[ni][j] = 0.f;
#pragma unroll
  for (int mi = 0; mi < 4; ++mi) {
#pragma unroll
    for (int ni = 0; ni < 4; ++ni) {
      int colg = wc * 64 + ni * 16 + la;
      float bb = bv[colg];
#pragma unroll
      for (int j = 0; j < 4; ++j) {
        size_t rowg = m0 + wr * 64 + mi * 16 + lkq * 4 + j;
        float v = acc[mi][ni][j] + bb;
        vm[rowg * 128 + colg] = v;
        pacc[ni][j] = fmaf(w4[mi], v, pacc[ni][j]);
      }
    }
  }
  // cross-wave (wr) reduce into attL[a][col], a = lkq*4+j
  if (wr == 0) {
#pragma unroll
    for (int ni = 0; ni < 4; ++ni)
#pragma unroll
      for (int j = 0; j < 4; ++j)
        attL[(lkq * 4 + j) * 132 + wc * 64 + ni * 16 + la] = pacc[ni][j];
  }
  __syncthreads();
  if (wr == 1) {
#pragma unroll
    for (int ni = 0; ni < 4; ++ni)
#pragma unroll
      for (int j = 0; j < 4; ++j)
        attL[(lkq * 4 + j) * 132 + wc * 64 + ni * 16 + la] += pacc[ni][j];
  }
  __syncthreads();
  // write attended (2048 f32) + q1 (16)
#pragma unroll
  for (int i = 0; i < 2; ++i) {
    int fidx = tid + i * 256;
    int a = fidx >> 5, c = (fidx & 31) * 4;
    f32x4 vv = *(const f32x4*)(attL + a * 132 + c);
    *(f32x4*)(att + (size_t)b * 2048 + a * 128 + c) = vv;
  }
  for (int j = wave; j < 16; j += 4) {
    float p = task[(size_t)b * 1024 + lane] * attL[j * 132 + lane]
            + task[(size_t)b * 1024 + 64 + lane] * attL[j * 132 + 64 + lane];
    p = wave_sum(p);
    if (lane == 0) q1[(size_t)b * 16 + j] = p;
  }
}

extern "C" void kernel_launch(void* const* d_in, const int* in_sizes, int n_in,
                              void* d_out, int out_size, void* d_ws, size_t ws_size,
                              hipStream_t stream) {
  const float* basis = (const float*)d_in[0];
  const float* sf    = (const float*)d_in[1];
  const float* task  = (const float*)d_in[2];
  const float* mask  = (const float*)d_in[3];
  const float* Wq    = (const float*)d_in[4];
  const float* Wk    = (const float*)d_in[5];
  const float* bk    = (const float*)d_in[6];
  const float* Wv    = (const float*)d_in[7];
  const float* bv    = (const float*)d_in[8];

  float* out  = (float*)d_out;
  float* q1   = out;
  float* att  = out + OFF_ATT;
  float* logi = out + OFF_LOG;
  float* wts  = out + OFF_W;
  float* km   = out + OFF_KM;
  float* vm   = out + OFF_VM;
  float* simo = out + OFF_SIM;

  // Stash plan (every stash is consumed by kernels that COMPLETE before the
  // kernel that overwrites its region launches — stream-ordered, no intra-kernel
  // read/write overlap):
  //  - Abf (bf16 131072x2304 = 604MB) in the vm region (1GB); consumed by the
  //    qk_gemms, both of which finish before v_gemm_attend (which writes vm).
  //  - query/invn/WkT/WqT in the att region; all consumed before v_gemm_attend
  //    (the only writer of att) launches. Wv is NOT stashed (round-3 race);
  //    v_gemm_attend stages it from the immutable input directly.
  float* query = att;                                       // 6,291,456 f32
  float* invn  = att + 6291456;                             //   131,072 f32
  unsigned short* WkT = (unsigned short*)(att + 6422528);   //   884,736 bf16
  unsigned short* WqT = WkT + 884736;                       //   884,736 bf16
  unsigned short* Abf = (unsigned short*)vm;                // 301,989,888 bf16

  norm_kernel<<<32768, 256, 0, stream>>>(task, invn, simo);
  wprep_t<<<216, 256, 0, stream>>>(Wk, WkT, 2304, 384);
  wprep_t<<<216, 256, 0, stream>>>(Wq, WqT, 2304, 384);
  abuild_sim<<<16384, 576, 0, stream>>>(basis, sf, task, invn, Abf, simo);
  // keys: M=131072, N=384 (3 n-tiles), K=2304; bias + mask
  qk_gemm<0><<<3072, 256, 0, stream>>>(Abf, WkT, bk, mask, km);
  // query: M=16384 (Abf rows stride 8), N=384, K=2304
  qk_gemm<1><<<384, 256, 0, stream>>>(Abf, WqT, nullptr, nullptr, query);
  attn_kernel<<<16384, 256, 0, stream>>>(query, km, logi, wts);
  // values GEMM + fused attend/q1: M=2,097,152, N=128, K=128 (overwrites Abf stash)
  v_gemm_attend<<<16384, 256, 0, stream>>>(sf, Wv, bv, wts, task, vm, att, q1);
}